// Round 1
// baseline (364.765 us; speedup 1.0000x reference)
//
#include <hip/hip_runtime.h>
#include <math.h>

// Problem constants (from reference setup_inputs)
#define BB 16
#define CC 85
#define HH 128
#define WW 128
#define NGT 64
#define HW (HH * WW)          // 16384
#define NC (CC - 5)           // 80

// ws layout (doubles): [0] = obj acc (softplus sum - gathered), [1] = cls acc, [2] = box sum

__device__ __forceinline__ float softplus_f(float x) {
    // logaddexp(x, 0) = max(x,0) + log1p(exp(-|x|)); fast intrinsics are
    // accurate to ~1e-7 rel here since exp(-|x|) in (0,1] so 1+e has no
    // catastrophic cancellation, and absolute per-element error divides by
    // HW (16384) / HW*nc (1.3M) in the final means.
    float ax = fabsf(x);
    float e = __expf(-ax);
    return fmaxf(x, 0.0f) + __logf(1.0f + e);
}

// Dense softplus sum over channels 4..84. Grid: (81*16, BB) blocks x 256 thr.
// Each block covers 256 float4 = 1024 elements of exactly ONE channel slice,
// so the obj-vs-cls accumulator choice is block-uniform.
__global__ __launch_bounds__(256) void bce_sum_kernel(const float* __restrict__ preds,
                                                      double* __restrict__ acc) {
    const int b = blockIdx.y;
    const int c = 4 + (blockIdx.x >> 4);                 // 16 blocks per channel
    const int q4 = ((blockIdx.x & 15) << 8) + threadIdx.x; // float4 idx in channel
    const float4* p = (const float4*)(preds + ((size_t)(b * CC + c) * HW));
    float4 v = p[q4];
    float s = softplus_f(v.x) + softplus_f(v.y) + softplus_f(v.z) + softplus_f(v.w);

    // wave64 reduce
    #pragma unroll
    for (int off = 32; off > 0; off >>= 1) s += __shfl_down(s, off, 64);

    __shared__ float wsum[4];
    const int lane = threadIdx.x & 63;
    const int wv = threadIdx.x >> 6;
    if (lane == 0) wsum[wv] = s;
    __syncthreads();
    if (threadIdx.x == 0) {
        float tot = wsum[0] + wsum[1] + wsum[2] + wsum[3];
        atomicAdd(&acc[(c == 4) ? 0 : 1], (double)tot);
    }
}

// Per-GT work: gather boxes + obj/cls logits, IoU, set-semantics dedup.
// Grid: BB blocks x 64 threads (one wave; one GT per lane).
__global__ __launch_bounds__(64) void gt_kernel(const float* __restrict__ preds,
                                                const float* __restrict__ tgt,
                                                double* __restrict__ acc) {
    const int b = blockIdx.x;
    const int n = threadIdx.x;
    const float* t = tgt + ((size_t)(b * NGT + n)) * 5;
    const int cls = (int)t[0];
    const float cx = t[1], cy = t[2], w = t[3], h = t[4];
    const int gi = (int)(cx * (float)WW);
    const int gj = (int)(cy * (float)HH);
    const int idx = gj * WW + gi;

    const float* pb = preds + (size_t)b * CC * HW + idx;
    const float px   = pb[0 * HW];
    const float py   = pb[1 * HW];
    const float pw   = pb[2 * HW];
    const float ph   = pb[3 * HW];
    const float pobj = pb[4 * HW];
    const float pcls = pb[(5 + cls) * HW];

    // boxes exactly as the reference computes them
    const float p0 = px - pw * 0.5f, p1 = py - ph * 0.5f;
    const float p2 = px + pw * 0.5f, p3 = py + ph * 0.5f;
    const float g0 = (cx - w * 0.5f) * WW, g1 = (cy - h * 0.5f) * HH;
    const float g2 = (cx + w * 0.5f) * WW, g3 = (cy + h * 0.5f) * HH;

    const float ix1 = fmaxf(p0, g0), iy1 = fmaxf(p1, g1);
    const float ix2 = fminf(p2, g2), iy2 = fminf(p3, g3);
    const float inter = fmaxf(ix2 - ix1, 0.0f) * fmaxf(iy2 - iy1, 0.0f);
    const float a1 = (p2 - p0) * (p3 - p1);
    const float a2 = (g2 - g0) * (g3 - g1);
    const float iou = inter / (a1 + a2 - inter + 1e-7f);
    float box = 1.0f - iou;

    // set-semantics dedup: obj_tgt.at[b, idx].set(1) counts a cell once;
    // cls_tgt.at[b, idx, cls].set(1) counts a (cell, cls) pair once.
    __shared__ int s_idx[NGT];
    __shared__ int s_cls[NGT];
    s_idx[n] = idx;
    s_cls[n] = cls;
    __syncthreads();
    bool dup_o = false, dup_c = false;
    for (int m = 0; m < n; ++m) {
        if (s_idx[m] == idx) {
            dup_o = true;
            if (s_cls[m] == cls) dup_c = true;
        }
    }
    float sub_o = dup_o ? 0.0f : pobj;
    float sub_c = dup_c ? 0.0f : pcls;

    #pragma unroll
    for (int off = 32; off > 0; off >>= 1) {
        box   += __shfl_down(box,   off, 64);
        sub_o += __shfl_down(sub_o, off, 64);
        sub_c += __shfl_down(sub_c, off, 64);
    }
    if (n == 0) {
        atomicAdd(&acc[2], (double)box);
        atomicAdd(&acc[0], (double)(-sub_o));
        atomicAdd(&acc[1], (double)(-sub_c));
    }
}

__global__ void fin_kernel(const double* __restrict__ acc, float* __restrict__ out) {
    const double obj = acc[0] / (double)HW;
    const double cls = acc[1] / ((double)HW * (double)NC);
    const double box = acc[2];
    out[0] = (float)(0.05 * box + 1.0 * obj + 0.5 * cls);
}

extern "C" void kernel_launch(void* const* d_in, const int* in_sizes, int n_in,
                              void* d_out, int out_size, void* d_ws, size_t ws_size,
                              hipStream_t stream) {
    const float* preds = (const float*)d_in[0];
    const float* targets = (const float*)d_in[1];
    float* out = (float*)d_out;
    double* acc = (double*)d_ws;

    hipMemsetAsync(acc, 0, 3 * sizeof(double), stream);

    dim3 grid_bce(81 * 16, BB);   // 16 blocks of 256 thr per channel slice
    bce_sum_kernel<<<grid_bce, 256, 0, stream>>>(preds, acc);
    gt_kernel<<<BB, 64, 0, stream>>>(preds, targets, acc);
    fin_kernel<<<1, 1, 0, stream>>>(acc, out);
}

// Round 2
// 143.646 us; speedup vs baseline: 2.5393x; 2.5393x over previous
//
#include <hip/hip_runtime.h>
#include <math.h>

// Problem constants (from reference setup_inputs)
#define BB 16
#define CC 85
#define HH 128
#define WW 128
#define NGT 64
#define HW (HH * WW)          // 16384
#define NC (CC - 5)           // 80
#define NCH 81                // channels 4..84 (obj + 80 cls)
#define NPART (BB * NCH)      // 1296 partial sums

// ws layout:
//   [0 .. NPART)  floats : per-block partial softplus sums (block = b*81 + (c-4))
//   then (8-byte aligned) 3 doubles: [0]=obj gathered-sub, [1]=cls gathered-sub, [2]=box sum

__device__ __forceinline__ float softplus_f(float x) {
    // logaddexp(x,0) = max(x,0) + log1p(exp(-|x|)); exp(-|x|) in (0,1] so no
    // cancellation; ~1e-7 rel error, and the final means divide by 16384 / 1.3M.
    float ax = fabsf(x);
    float e = __expf(-ax);
    return fmaxf(x, 0.0f) + __logf(1.0f + e);
}

// Dense softplus sum over channels 4..84. Grid: NPART blocks x 256 thr.
// Block bk covers channel slice (b = bk/81, c = 4 + bk%81): 16384 elems =
// 4096 float4 = 256 threads x 16 float4 each. One partial-store per block,
// distinct address -> zero atomic contention.
__global__ __launch_bounds__(256) void bce_sum_kernel(const float* __restrict__ preds,
                                                      float* __restrict__ part) {
    const int bk = blockIdx.x;
    const int b = bk / NCH;
    const int c = 4 + (bk - b * NCH);
    const float4* p = (const float4*)(preds + ((size_t)(b * CC + c) * HW));

    float s = 0.0f;
    #pragma unroll
    for (int k = 0; k < 16; ++k) {
        float4 v = p[threadIdx.x + (k << 8)];
        s += softplus_f(v.x) + softplus_f(v.y) + softplus_f(v.z) + softplus_f(v.w);
    }

    // wave64 reduce
    #pragma unroll
    for (int off = 32; off > 0; off >>= 1) s += __shfl_down(s, off, 64);

    __shared__ float wsum[4];
    const int lane = threadIdx.x & 63;
    const int wv = threadIdx.x >> 6;
    if (lane == 0) wsum[wv] = s;
    __syncthreads();
    if (threadIdx.x == 0) part[bk] = wsum[0] + wsum[1] + wsum[2] + wsum[3];
}

// Per-GT work: gather boxes + obj/cls logits, IoU, set-semantics dedup.
// Grid: BB blocks x 64 threads (one wave; one GT per lane). Only 48 atomics
// total -> contention negligible.
__global__ __launch_bounds__(64) void gt_kernel(const float* __restrict__ preds,
                                                const float* __restrict__ tgt,
                                                double* __restrict__ acc) {
    const int b = blockIdx.x;
    const int n = threadIdx.x;
    const float* t = tgt + ((size_t)(b * NGT + n)) * 5;
    const int cls = (int)t[0];
    const float cx = t[1], cy = t[2], w = t[3], h = t[4];
    const int gi = (int)(cx * (float)WW);
    const int gj = (int)(cy * (float)HH);
    const int idx = gj * WW + gi;

    const float* pb = preds + (size_t)b * CC * HW + idx;
    const float px   = pb[0 * HW];
    const float py   = pb[1 * HW];
    const float pw   = pb[2 * HW];
    const float ph   = pb[3 * HW];
    const float pobj = pb[4 * HW];
    const float pcls = pb[(5 + cls) * HW];

    // boxes exactly as the reference computes them
    const float p0 = px - pw * 0.5f, p1 = py - ph * 0.5f;
    const float p2 = px + pw * 0.5f, p3 = py + ph * 0.5f;
    const float g0 = (cx - w * 0.5f) * WW, g1 = (cy - h * 0.5f) * HH;
    const float g2 = (cx + w * 0.5f) * WW, g3 = (cy + h * 0.5f) * HH;

    const float ix1 = fmaxf(p0, g0), iy1 = fmaxf(p1, g1);
    const float ix2 = fminf(p2, g2), iy2 = fminf(p3, g3);
    const float inter = fmaxf(ix2 - ix1, 0.0f) * fmaxf(iy2 - iy1, 0.0f);
    const float a1 = (p2 - p0) * (p3 - p1);
    const float a2 = (g2 - g0) * (g3 - g1);
    const float iou = inter / (a1 + a2 - inter + 1e-7f);
    float box = 1.0f - iou;

    // set-semantics dedup: a cell counts once for obj; a (cell,cls) pair once.
    __shared__ int s_idx[NGT];
    __shared__ int s_cls[NGT];
    s_idx[n] = idx;
    s_cls[n] = cls;
    __syncthreads();
    bool dup_o = false, dup_c = false;
    for (int m = 0; m < n; ++m) {
        if (s_idx[m] == idx) {
            dup_o = true;
            if (s_cls[m] == cls) dup_c = true;
        }
    }
    float sub_o = dup_o ? 0.0f : pobj;
    float sub_c = dup_c ? 0.0f : pcls;

    #pragma unroll
    for (int off = 32; off > 0; off >>= 1) {
        box   += __shfl_down(box,   off, 64);
        sub_o += __shfl_down(sub_o, off, 64);
        sub_c += __shfl_down(sub_c, off, 64);
    }
    if (n == 0) {
        atomicAdd(&acc[2], (double)box);
        atomicAdd(&acc[0], (double)(-sub_o));
        atomicAdd(&acc[1], (double)(-sub_c));
    }
}

// Reduce the 1296 partials (+ gathered-term accumulators) into the scalar.
__global__ __launch_bounds__(256) void fin_kernel(const float* __restrict__ part,
                                                  const double* __restrict__ acc,
                                                  float* __restrict__ out) {
    double obj = 0.0, cls = 0.0;
    for (int k = threadIdx.x; k < NPART; k += 256) {
        double v = (double)part[k];
        // k % 81 == 0  <=>  c == 4 (obj channel)
        if (k % NCH == 0) obj += v; else cls += v;
    }
    __shared__ double so[256], sc[256];
    so[threadIdx.x] = obj;
    sc[threadIdx.x] = cls;
    __syncthreads();
    for (int s = 128; s > 0; s >>= 1) {
        if (threadIdx.x < s) {
            so[threadIdx.x] += so[threadIdx.x + s];
            sc[threadIdx.x] += sc[threadIdx.x + s];
        }
        __syncthreads();
    }
    if (threadIdx.x == 0) {
        double o = (so[0] + acc[0]) / (double)HW;
        double c = (sc[0] + acc[1]) / ((double)HW * (double)NC);
        double bx = acc[2];
        out[0] = (float)(0.05 * bx + 1.0 * o + 0.5 * c);
    }
}

extern "C" void kernel_launch(void* const* d_in, const int* in_sizes, int n_in,
                              void* d_out, int out_size, void* d_ws, size_t ws_size,
                              hipStream_t stream) {
    const float* preds = (const float*)d_in[0];
    const float* targets = (const float*)d_in[1];
    float* out = (float*)d_out;

    float* part = (float*)d_ws;
    // 8-byte aligned doubles after the partials
    size_t acc_off = ((size_t)NPART * sizeof(float) + 7) & ~(size_t)7;
    double* acc = (double*)((char*)d_ws + acc_off);

    hipMemsetAsync(acc, 0, 3 * sizeof(double), stream);

    bce_sum_kernel<<<NPART, 256, 0, stream>>>(preds, part);
    gt_kernel<<<BB, 64, 0, stream>>>(preds, targets, acc);
    fin_kernel<<<1, 256, 0, stream>>>(part, acc, out);
}